// Round 3
// baseline (327.246 us; speedup 1.0000x reference)
//
#include <hip/hip_runtime.h>

#define N_NODES 50000
#define N_EDGES 800000
#define D 128
#define K2 256                         // fused GEMM K dimension
#define NBKT ((N_NODES + 255) / 256)   // 196 buckets of 256 nodes
#define BCAP 8192                      // fixed slots per bucket (64 sigma safe)
#define EPB 2048                       // edges per k_part block
#define LDA 136                        // LDS row stride in ushorts (128 + 8 pad)

typedef unsigned short u16;
typedef unsigned int   u32;
typedef short bf16x8 __attribute__((ext_vector_type(8)));
typedef float f32x16 __attribute__((ext_vector_type(16)));

// f32 -> bf16 (round-to-nearest-even)
__device__ __forceinline__ u16 f2b(float x) {
    union { float f; u32 u; } c; c.f = x;
    u32 r = c.u + 0x7FFFu + ((c.u >> 16) & 1u);
    return (u16)(r >> 16);
}
__device__ __forceinline__ float b2f(u16 u) {
    union { u32 u; float f; } c; c.u = ((u32)u) << 16;
    return c.f;
}

// ---------------------------------------------------------------------------
// B1: partition edges into fixed-capacity bucket chunks of ebuf.
// ---------------------------------------------------------------------------
__global__ __launch_bounds__(256) void k_part(const int* __restrict__ src,
                                              const int* __restrict__ dst,
                                              int* __restrict__ gbfill,
                                              u32* __restrict__ ebuf) {
    __shared__ u16 ls[EPB], ld_[EPB];
    __shared__ int hist[NBKT], lcnt[NBKT], basev[NBKT];
    const int e0 = blockIdx.x * EPB;
    for (int t = threadIdx.x; t < NBKT; t += 256) { hist[t] = 0; lcnt[t] = 0; }
    __syncthreads();
#pragma unroll
    for (int j = 0; j < EPB / 256; ++j) {
        int t = j * 256 + (int)threadIdx.x;
        int e = e0 + t;
        if (e < N_EDGES) {
            int d = dst[e];
            ls[t] = (u16)src[e];
            ld_[t] = (u16)d;
            atomicAdd(&hist[d >> 8], 1);
        }
    }
    __syncthreads();
    for (int t = threadIdx.x; t < NBKT; t += 256)
        basev[t] = t * BCAP + (hist[t] ? atomicAdd(&gbfill[t], hist[t]) : 0);
    __syncthreads();
#pragma unroll
    for (int j = 0; j < EPB / 256; ++j) {
        int t = j * 256 + (int)threadIdx.x;
        int e = e0 + t;
        if (e < N_EDGES) {
            int d = (int)ld_[t];
            int b = d >> 8;
            int o = atomicAdd(&lcnt[b], 1);
            ebuf[basev[b] + o] = (u32)ls[t] | ((u32)(d & 255) << 16);
        }
    }
}

// ---------------------------------------------------------------------------
// B2: per-bucket build: LDS degree hist + scan -> row_off/degv/rcp, csr fill.
// ---------------------------------------------------------------------------
__global__ __launch_bounds__(256) void k_build(const u32* __restrict__ ebuf,
                                               const int* __restrict__ gbfill,
                                               int* __restrict__ row_off,
                                               u16* __restrict__ degv,
                                               float* __restrict__ rcp,
                                               u16* __restrict__ csr) {
    __shared__ int dcnt[256], fcnt[256], sdata[256];
    const int b = blockIdx.x;
    const int beg = b * BCAP;
    const int end = beg + gbfill[b];
    dcnt[threadIdx.x] = 0;
    fcnt[threadIdx.x] = 0;
    __syncthreads();
    for (int j = beg + (int)threadIdx.x; j < end; j += 256)
        atomicAdd(&dcnt[(ebuf[j] >> 16) & 255], 1);
    __syncthreads();
    int v = dcnt[threadIdx.x];
    sdata[threadIdx.x] = v;
    __syncthreads();
#pragma unroll
    for (int off = 1; off < 256; off <<= 1) {
        int t = (threadIdx.x >= (unsigned)off) ? sdata[threadIdx.x - off] : 0;
        __syncthreads();
        sdata[threadIdx.x] += t;
        __syncthreads();
    }
    int node = (b << 8) + (int)threadIdx.x;
    if (node < N_NODES) {
        row_off[node] = beg + sdata[threadIdx.x] - v;   // exclusive prefix
        degv[node] = (u16)v;
        rcp[node] = 1.0f / (float)max(v, 1);
    }
    for (int j = beg + (int)threadIdx.x; j < end; j += 256) {
        u32 u = ebuf[j];
        int ln = (u >> 16) & 255;
        int o = atomicAdd(&fcnt[ln], 1);
        csr[beg + (sdata[ln] - dcnt[ln]) + o] = (u16)(u & 0xFFFFu);
    }
}

// ---------------------------------------------------------------------------
// K4: cast features f32 -> bf16 (8 elems/thread)
// ---------------------------------------------------------------------------
__global__ __launch_bounds__(256) void k_cast(const float* __restrict__ f,
                                              u16* __restrict__ o) {
    int idx = blockIdx.x * 256 + (int)threadIdx.x;
    if (idx < N_NODES * (D / 8)) {
        const float4* fp = (const float4*)(f + (size_t)idx * 8);
        float4 a = fp[0], b = fp[1];
        uint4 p;
        p.x = (u32)f2b(a.x) | ((u32)f2b(a.y) << 16);
        p.y = (u32)f2b(a.z) | ((u32)f2b(a.w) << 16);
        p.z = (u32)f2b(b.x) | ((u32)f2b(b.y) << 16);
        p.w = (u32)f2b(b.z) | ((u32)f2b(b.w) << 16);
        ((uint4*)o)[idx] = p;
    }
}

// ---------------------------------------------------------------------------
// K5: build concatenated transposed weights per layer:
// Wcat[l][n][k], k in [0,256): k<128 from W_self[l], k>=128 from W_neigh[l].
// ---------------------------------------------------------------------------
__global__ __launch_bounds__(256) void k_prepw(
        const float* __restrict__ w0, const float* __restrict__ w1,
        const float* __restrict__ w2, const float* __restrict__ w3,
        const float* __restrict__ w4, const float* __restrict__ w5,
        u16* __restrict__ wt) {
    const int idx = (int)blockIdx.y * 2 + ((int)blockIdx.x >= 4 ? 1 : 0);
    const float* W;
    switch (idx) {
        case 0: W = w0; break; case 1: W = w1; break; case 2: W = w2; break;
        case 3: W = w3; break; case 4: W = w4; break; default: W = w5; break;
    }
    u16* out = wt + (size_t)blockIdx.y * D * K2;
    const int k0g = blockIdx.x * 32;        // global k in [0,256)
    const int k0s = k0g & (D - 1);          // source row in [0,128)
    __shared__ float s[32][129];
    for (int t = threadIdx.x; t < 32 * 32; t += 256) {
        int r = t >> 5, c4 = t & 31;
        float4 v = ((const float4*)&W[(size_t)(k0s + r) * D])[c4];
        s[r][c4 * 4 + 0] = v.x; s[r][c4 * 4 + 1] = v.y;
        s[r][c4 * 4 + 2] = v.z; s[r][c4 * 4 + 3] = v.w;
    }
    __syncthreads();
    for (int t = threadIdx.x; t < 512; t += 256) {
        int n = t >> 2, g = t & 3;
        uint4 p;
        p.x = (u32)f2b(s[g * 8 + 0][n]) | ((u32)f2b(s[g * 8 + 1][n]) << 16);
        p.y = (u32)f2b(s[g * 8 + 2][n]) | ((u32)f2b(s[g * 8 + 3][n]) << 16);
        p.z = (u32)f2b(s[g * 8 + 4][n]) | ((u32)f2b(s[g * 8 + 5][n]) << 16);
        p.w = (u32)f2b(s[g * 8 + 6][n]) | ((u32)f2b(s[g * 8 + 7][n]) << 16);
        *(uint4*)&out[(size_t)n * K2 + k0g + g * 8] = p;
    }
}

// ---------------------------------------------------------------------------
// K8: fully fused layer: out = act( [h | mean_agg(h)] @ Wcat + b ).
// Block = 64 dst rows, 256 threads, 4 waves 2x2 MFMA tiling.
// Schedule:
//   1. stage As(self) + Ws(k 0..127) -> sync
//   2. preload Ws(k 128..255) into registers (no LDS dep)
//   3. MFMA chunk0 (self @ W_self)   -> sync (As,Ws free)
//   4. ds_write Ws chunk1 from regs; gather-aggregate 64 nodes into As
//      (16 groups x 16 lanes, 8-deep gather pipeline per group)  -> sync
//   5. MFMA chunk1 (mean @ W_neigh), epilogue
// Eliminates the mb round-trip (25.6 MB/layer) and hides GEMM + W traffic
// under the fabric-bound gather phase.
// ---------------------------------------------------------------------------
__global__ __launch_bounds__(256) void k_fused(
        const u16* __restrict__ h, const int* __restrict__ row_off,
        const u16* __restrict__ degv, const u16* __restrict__ csr,
        const float* __restrict__ rcp, const u16* __restrict__ Wt,
        const float* __restrict__ bias, void* __restrict__ outp,
        int relu, int f32out) {
    const int row0 = blockIdx.x * 64;

    __shared__ u16 As[64 * LDA];    // 17.0 KB (self chunk, then mean chunk)
    __shared__ u16 Ws[128 * LDA];   // 34.8 KB (k-chunk 0, then k-chunk 1)

    const int tid  = (int)threadIdx.x;
    const int lane = tid & 63;
    const int wave = tid >> 6;
    const int wm = wave & 1;    // row band (32 rows)
    const int wn = wave >> 1;   // col half (64 cols)
    const int m  = lane & 31;
    const int kh = lane >> 5;   // k-half within 16-chunk

    f32x16 acc0, acc1;
#pragma unroll
    for (int i = 0; i < 16; ++i) { acc0[i] = 0.0f; acc1[i] = 0.0f; }

    // ---- stage As (self rows) + Ws chunk0 ----
    for (int t = tid; t < 1024; t += 256) {
        int r = t >> 4, cc = t & 15;
        int row = row0 + r; if (row >= N_NODES) row = N_NODES - 1;
        *(float4*)&As[r * LDA + cc * 8] = ((const float4*)&h[(size_t)row * D])[cc];
    }
    for (int t = tid; t < 2048; t += 256) {
        int r = t >> 4, cc = t & 15;
        *(float4*)&Ws[r * LDA + cc * 8] = *(const float4*)&Wt[(size_t)r * K2 + cc * 8];
    }
    __syncthreads();

    // ---- preload Ws chunk1 into registers (L2-hot, no LDS dependency) ----
    float4 w1r[8];
#pragma unroll
    for (int j = 0; j < 8; ++j) {
        int t = tid + j * 256;
        int r = t >> 4, cc = t & 15;
        w1r[j] = *(const float4*)&Wt[(size_t)r * K2 + 128 + cc * 8];
    }

    // ---- MFMA chunk0: self @ W_self ----
    const u16* ap  = &As[(wm * 32 + m) * LDA + kh * 8];
    const u16* bp0 = &Ws[(wn * 64 + m) * LDA + kh * 8];
    const u16* bp1 = bp0 + 32 * LDA;
#pragma unroll
    for (int kk = 0; kk < 8; ++kk) {
        bf16x8 a  = *(const bf16x8*)(ap  + kk * 16);
        bf16x8 b0 = *(const bf16x8*)(bp0 + kk * 16);
        bf16x8 b1 = *(const bf16x8*)(bp1 + kk * 16);
        acc0 = __builtin_amdgcn_mfma_f32_32x32x16_bf16(a, b0, acc0, 0, 0, 0);
        acc1 = __builtin_amdgcn_mfma_f32_32x32x16_bf16(a, b1, acc1, 0, 0, 0);
    }
    __syncthreads();   // all waves done reading As (self) and Ws (chunk0)

    // ---- write Ws chunk1 from registers ----
#pragma unroll
    for (int j = 0; j < 8; ++j) {
        int t = tid + j * 256;
        int r = t >> 4, cc = t & 15;
        *(float4*)&Ws[r * LDA + cc * 8] = w1r[j];
    }

    // ---- gather-aggregate this block's 64 nodes into As ----
    {
        const int g  = tid >> 4;            // group 0..15
        const int cl = tid & 15;            // 16B chunk within row
        const size_t coff = (size_t)cl * 8;
#pragma unroll
        for (int s = 0; s < 4; ++s) {
            const int r = g + s * 16;       // local row, stride-16 balance
            const int v = row0 + r;
            float ax[8];
#pragma unroll
            for (int i = 0; i < 8; ++i) ax[i] = 0.0f;
            float rv = 0.0f;
            if (v < N_NODES) {
                const int beg = row_off[v];
                const int end = beg + (int)degv[v];
                rv = rcp[v];
                int j = beg;
                for (; j + 8 <= end; j += 8) {   // 8 gathers in flight
                    int u0 = csr[j + 0], u1 = csr[j + 1], u2 = csr[j + 2], u3 = csr[j + 3];
                    int u4 = csr[j + 4], u5 = csr[j + 5], u6 = csr[j + 6], u7 = csr[j + 7];
                    bf16x8 x0 = *(const bf16x8*)&h[(size_t)u0 * D + coff];
                    bf16x8 x1 = *(const bf16x8*)&h[(size_t)u1 * D + coff];
                    bf16x8 x2 = *(const bf16x8*)&h[(size_t)u2 * D + coff];
                    bf16x8 x3 = *(const bf16x8*)&h[(size_t)u3 * D + coff];
                    bf16x8 x4 = *(const bf16x8*)&h[(size_t)u4 * D + coff];
                    bf16x8 x5 = *(const bf16x8*)&h[(size_t)u5 * D + coff];
                    bf16x8 x6 = *(const bf16x8*)&h[(size_t)u6 * D + coff];
                    bf16x8 x7 = *(const bf16x8*)&h[(size_t)u7 * D + coff];
#pragma unroll
                    for (int i = 0; i < 8; ++i)
                        ax[i] += ((b2f((u16)x0[i]) + b2f((u16)x1[i])) +
                                  (b2f((u16)x2[i]) + b2f((u16)x3[i]))) +
                                 ((b2f((u16)x4[i]) + b2f((u16)x5[i])) +
                                  (b2f((u16)x6[i]) + b2f((u16)x7[i])));
                }
                for (; j + 2 <= end; j += 2) {
                    int u0 = csr[j], u1 = csr[j + 1];
                    bf16x8 x0 = *(const bf16x8*)&h[(size_t)u0 * D + coff];
                    bf16x8 x1 = *(const bf16x8*)&h[(size_t)u1 * D + coff];
#pragma unroll
                    for (int i = 0; i < 8; ++i)
                        ax[i] += b2f((u16)x0[i]) + b2f((u16)x1[i]);
                }
                if (j < end) {
                    int u0 = csr[j];
                    bf16x8 x0 = *(const bf16x8*)&h[(size_t)u0 * D + coff];
#pragma unroll
                    for (int i = 0; i < 8; ++i) ax[i] += b2f((u16)x0[i]);
                }
            }
            uint4 p;
            p.x = (u32)f2b(ax[0] * rv) | ((u32)f2b(ax[1] * rv) << 16);
            p.y = (u32)f2b(ax[2] * rv) | ((u32)f2b(ax[3] * rv) << 16);
            p.z = (u32)f2b(ax[4] * rv) | ((u32)f2b(ax[5] * rv) << 16);
            p.w = (u32)f2b(ax[6] * rv) | ((u32)f2b(ax[7] * rv) << 16);
            *(uint4*)&As[r * LDA + cl * 8] = p;
        }
    }
    __syncthreads();

    // ---- MFMA chunk1: mean @ W_neigh ----
#pragma unroll
    for (int kk = 0; kk < 8; ++kk) {
        bf16x8 a  = *(const bf16x8*)(ap  + kk * 16);
        bf16x8 b0 = *(const bf16x8*)(bp0 + kk * 16);
        bf16x8 b1 = *(const bf16x8*)(bp1 + kk * 16);
        acc0 = __builtin_amdgcn_mfma_f32_32x32x16_bf16(a, b0, acc0, 0, 0, 0);
        acc1 = __builtin_amdgcn_mfma_f32_32x32x16_bf16(a, b1, acc1, 0, 0, 0);
    }

    // ---- epilogue: col = lane&31, row = (r&3) + 8*(r>>2) + 4*(lane>>5) ----
    const int c0 = wn * 64 + m;
    const int c1 = c0 + 32;
    const float b0v = bias[c0];
    const float b1v = bias[c1];
#pragma unroll
    for (int r = 0; r < 16; ++r) {
        int rowl = (r & 3) + 8 * (r >> 2) + 4 * kh;
        int grow = row0 + wm * 32 + rowl;
        if (grow < N_NODES) {
            float o0 = acc0[r] + b0v;
            float o1 = acc1[r] + b1v;
            if (relu) { o0 = fmaxf(o0, 0.0f); o1 = fmaxf(o1, 0.0f); }
            if (f32out) {
                ((float*)outp)[(size_t)grow * D + c0] = o0;
                ((float*)outp)[(size_t)grow * D + c1] = o1;
            } else {
                ((u16*)outp)[(size_t)grow * D + c0] = f2b(o0);
                ((u16*)outp)[(size_t)grow * D + c1] = f2b(o1);
            }
        }
    }
}

// ---------------------------------------------------------------------------
extern "C" void kernel_launch(void* const* d_in, const int* in_sizes, int n_in,
                              void* d_out, int out_size, void* d_ws, size_t ws_size,
                              hipStream_t stream) {
    const float* features = (const float*)d_in[0];
    const int*   edge_src = (const int*)d_in[1];
    const int*   edge_dst = (const int*)d_in[2];
    const float* Wself[3] = {(const float*)d_in[3], (const float*)d_in[6], (const float*)d_in[9]};
    const float* Wngh[3]  = {(const float*)d_in[4], (const float*)d_in[7], (const float*)d_in[10]};
    const float* bias[3]  = {(const float*)d_in[5], (const float*)d_in[8], (const float*)d_in[11]};
    float* out = (float*)d_out;

    char* ws = (char*)d_ws;
    size_t off = 0;
    auto alloc = [&](size_t bytes) {
        char* p = ws + off;
        off += (bytes + 255) & ~(size_t)255;
        return p;
    };
    int*   gbfill  = (int*)alloc(256 * sizeof(int));
    int*   row_off = (int*)alloc(N_NODES * sizeof(int));
    u16*   degv    = (u16*)alloc(N_NODES * sizeof(u16));
    float* rcp     = (float*)alloc(N_NODES * sizeof(float));
    u32*   ebuf    = (u32*)alloc((size_t)NBKT * BCAP * sizeof(u32));
    u16*   csr     = (u16*)alloc((size_t)NBKT * BCAP * sizeof(u16));
    u16*   xa      = (u16*)alloc((size_t)N_NODES * D * sizeof(u16));
    u16*   xb      = (u16*)alloc((size_t)N_NODES * D * sizeof(u16));
    u16*   wt      = (u16*)alloc((size_t)3 * D * K2 * sizeof(u16));

    hipMemsetAsync(gbfill, 0, 256 * sizeof(int), stream);

    // CSR build (fixed-capacity buckets: no histogram/scan kernels)
    k_part<<<(N_EDGES + EPB - 1) / EPB, 256, 0, stream>>>(edge_src, edge_dst, gbfill, ebuf);
    k_build<<<NBKT, 256, 0, stream>>>(ebuf, gbfill, row_off, degv, rcp, csr);

    // bf16 prep
    k_cast<<<(N_NODES * (D / 8) + 255) / 256, 256, 0, stream>>>(features, xa);
    k_prepw<<<dim3(8, 3), 256, 0, stream>>>(Wself[0], Wngh[0], Wself[1], Wngh[1],
                                            Wself[2], Wngh[2], wt);

    const int gx = (N_NODES + 63) / 64;
    const size_t WSZ = (size_t)D * K2;

    // layer 0: xa -> xb (relu)
    k_fused<<<gx, 256, 0, stream>>>(xa, row_off, degv, csr, rcp, wt + 0 * WSZ,
                                    bias[0], xb, 1, 0);
    // layer 1: xb -> xa (relu)
    k_fused<<<gx, 256, 0, stream>>>(xb, row_off, degv, csr, rcp, wt + 1 * WSZ,
                                    bias[1], xa, 1, 0);
    // layer 2: xa -> out (f32, no act)
    k_fused<<<gx, 256, 0, stream>>>(xa, row_off, degv, csr, rcp, wt + 2 * WSZ,
                                    bias[2], out, 0, 1);
}

// Round 4
// 268.438 us; speedup vs baseline: 1.2191x; 1.2191x over previous
//
#include <hip/hip_runtime.h>

#define N_NODES 50000
#define N_EDGES 800000
#define D 128
#define K2 256                         // fused GEMM K dimension
#define NBKT ((N_NODES + 255) / 256)   // 196 buckets of 256 nodes
#define BCAP 8192                      // fixed slots per bucket (64 sigma safe)
#define EPB 2048                       // edges per k_part block
#define LDA 136                        // LDS row stride in ushorts (128 + 8 pad)
#define NCH 16                         // src-sort chunks (src>>12 -> 0..12 used)

typedef unsigned short u16;
typedef unsigned int   u32;
typedef short bf16x8 __attribute__((ext_vector_type(8)));
typedef float f32x16 __attribute__((ext_vector_type(16)));

// f32 -> bf16 (round-to-nearest-even)
__device__ __forceinline__ u16 f2b(float x) {
    union { float f; u32 u; } c; c.f = x;
    u32 r = c.u + 0x7FFFu + ((c.u >> 16) & 1u);
    return (u16)(r >> 16);
}
__device__ __forceinline__ float b2f(u16 u) {
    union { u32 u; float f; } c; c.u = ((u32)u) << 16;
    return c.f;
}

// ---------------------------------------------------------------------------
// B1: partition edges into fixed-capacity bucket chunks of ebuf.
// Per-block chunk reservation: one global atomic per bucket per block.
// Record: u32 = src (16b) | local_node (8b) << 16.
// ---------------------------------------------------------------------------
__global__ __launch_bounds__(256) void k_part(const int* __restrict__ src,
                                              const int* __restrict__ dst,
                                              int* __restrict__ gbfill,
                                              u32* __restrict__ ebuf) {
    __shared__ u16 ls[EPB], ld_[EPB];
    __shared__ int hist[NBKT], lcnt[NBKT], basev[NBKT];
    const int e0 = blockIdx.x * EPB;
    for (int t = threadIdx.x; t < NBKT; t += 256) { hist[t] = 0; lcnt[t] = 0; }
    __syncthreads();
#pragma unroll
    for (int j = 0; j < EPB / 256; ++j) {
        int t = j * 256 + (int)threadIdx.x;
        int e = e0 + t;
        if (e < N_EDGES) {
            int d = dst[e];
            ls[t] = (u16)src[e];
            ld_[t] = (u16)d;
            atomicAdd(&hist[d >> 8], 1);
        }
    }
    __syncthreads();
    for (int t = threadIdx.x; t < NBKT; t += 256)
        basev[t] = t * BCAP + (hist[t] ? atomicAdd(&gbfill[t], hist[t]) : 0);
    __syncthreads();
#pragma unroll
    for (int j = 0; j < EPB / 256; ++j) {
        int t = j * 256 + (int)threadIdx.x;
        int e = e0 + t;
        if (e < N_EDGES) {
            int d = (int)ld_[t];
            int b = d >> 8;
            int o = atomicAdd(&lcnt[b], 1);
            ebuf[basev[b] + o] = (u32)ls[t] | ((u32)(d & 255) << 16);
        }
    }
}

// ---------------------------------------------------------------------------
// B2: per-bucket build: LDS degree hist + scan -> row_off/degv/rcp, then
// csr fill COUNTING-SORTED BY src>>12 within each node's list. All nodes'
// lists are then walked in ascending-src order by k_aggm, so the whole
// grid sweeps the h table low->high in a ~1-2 MB moving window that stays
// L2-resident (4 MB/XCD) -> gathers become mostly L2 hits (~220cy) instead
// of L3 (~700cy). Latency is the gather limiter (MSHR-bound), so hit-rate
// directly multiplies throughput.
// ---------------------------------------------------------------------------
__global__ __launch_bounds__(256) void k_build(const u32* __restrict__ ebuf,
                                               const int* __restrict__ gbfill,
                                               int* __restrict__ row_off,
                                               u16* __restrict__ degv,
                                               float* __restrict__ rcp,
                                               u16* __restrict__ csr) {
    __shared__ int dcnt[256], sdata[256];
    __shared__ int c16[256][NCH];       // per-(node, src-chunk) counts->bases
    const int b = blockIdx.x;
    const int beg = b * BCAP;
    const int end = beg + gbfill[b];
    dcnt[threadIdx.x] = 0;
#pragma unroll
    for (int ch = 0; ch < NCH; ++ch) c16[threadIdx.x][ch] = 0;
    __syncthreads();
    for (int j = beg + (int)threadIdx.x; j < end; j += 256) {
        u32 u = ebuf[j];
        int ln = (u >> 16) & 255;
        atomicAdd(&dcnt[ln], 1);
        atomicAdd(&c16[ln][(int)(u & 0xFFFFu) >> 12], 1);
    }
    __syncthreads();
    int v = dcnt[threadIdx.x];
    sdata[threadIdx.x] = v;
    __syncthreads();
#pragma unroll
    for (int off = 1; off < 256; off <<= 1) {
        int t = (threadIdx.x >= (unsigned)off) ? sdata[threadIdx.x - off] : 0;
        __syncthreads();
        sdata[threadIdx.x] += t;
        __syncthreads();
    }
    int node = (b << 8) + (int)threadIdx.x;
    if (node < N_NODES) {
        row_off[node] = beg + sdata[threadIdx.x] - v;   // exclusive prefix
        degv[node] = (u16)v;
        rcp[node] = 1.0f / (float)max(v, 1);
    }
    // convert this node's chunk counts to running local bases
    {
        int run = sdata[threadIdx.x] - v;   // node's local exclusive base
#pragma unroll
        for (int ch = 0; ch < NCH; ++ch) {
            int c = c16[threadIdx.x][ch];
            c16[threadIdx.x][ch] = run;
            run += c;
        }
    }
    __syncthreads();
    for (int j = beg + (int)threadIdx.x; j < end; j += 256) {
        u32 u = ebuf[j];
        int ln = (u >> 16) & 255;
        int src = (int)(u & 0xFFFFu);
        int o = atomicAdd(&c16[ln][src >> 12], 1);
        csr[beg + o] = (u16)src;
    }
}

// ---------------------------------------------------------------------------
// K4: cast features f32 -> bf16 (8 elems/thread)
// ---------------------------------------------------------------------------
__global__ __launch_bounds__(256) void k_cast(const float* __restrict__ f,
                                              u16* __restrict__ o) {
    int idx = blockIdx.x * 256 + (int)threadIdx.x;
    if (idx < N_NODES * (D / 8)) {
        const float4* fp = (const float4*)(f + (size_t)idx * 8);
        float4 a = fp[0], b = fp[1];
        uint4 p;
        p.x = (u32)f2b(a.x) | ((u32)f2b(a.y) << 16);
        p.y = (u32)f2b(a.z) | ((u32)f2b(a.w) << 16);
        p.z = (u32)f2b(b.x) | ((u32)f2b(b.y) << 16);
        p.w = (u32)f2b(b.z) | ((u32)f2b(b.w) << 16);
        ((uint4*)o)[idx] = p;
    }
}

// ---------------------------------------------------------------------------
// K5: build concatenated transposed weights per layer:
// Wcat[l][n][k], k in [0,256): k<128 from W_self[l], k>=128 from W_neigh[l].
// ---------------------------------------------------------------------------
__global__ __launch_bounds__(256) void k_prepw(
        const float* __restrict__ w0, const float* __restrict__ w1,
        const float* __restrict__ w2, const float* __restrict__ w3,
        const float* __restrict__ w4, const float* __restrict__ w5,
        u16* __restrict__ wt) {
    const int idx = (int)blockIdx.y * 2 + ((int)blockIdx.x >= 4 ? 1 : 0);
    const float* W;
    switch (idx) {
        case 0: W = w0; break; case 1: W = w1; break; case 2: W = w2; break;
        case 3: W = w3; break; case 4: W = w4; break; default: W = w5; break;
    }
    u16* out = wt + (size_t)blockIdx.y * D * K2;
    const int k0g = blockIdx.x * 32;        // global k in [0,256)
    const int k0s = k0g & (D - 1);          // source row in [0,128)
    __shared__ float s[32][129];
    for (int t = threadIdx.x; t < 32 * 32; t += 256) {
        int r = t >> 5, c4 = t & 31;
        float4 v = ((const float4*)&W[(size_t)(k0s + r) * D])[c4];
        s[r][c4 * 4 + 0] = v.x; s[r][c4 * 4 + 1] = v.y;
        s[r][c4 * 4 + 2] = v.z; s[r][c4 * 4 + 3] = v.w;
    }
    __syncthreads();
    for (int t = threadIdx.x; t < 512; t += 256) {
        int n = t >> 2, g = t & 3;
        uint4 p;
        p.x = (u32)f2b(s[g * 8 + 0][n]) | ((u32)f2b(s[g * 8 + 1][n]) << 16);
        p.y = (u32)f2b(s[g * 8 + 2][n]) | ((u32)f2b(s[g * 8 + 3][n]) << 16);
        p.z = (u32)f2b(s[g * 8 + 4][n]) | ((u32)f2b(s[g * 8 + 5][n]) << 16);
        p.w = (u32)f2b(s[g * 8 + 6][n]) | ((u32)f2b(s[g * 8 + 7][n]) << 16);
        *(uint4*)&out[(size_t)n * K2 + k0g + g * 8] = p;
    }
}

// ---------------------------------------------------------------------------
// K6: fused-layer MFMA GEMM: out = act( [h|m] @ Wcat + b ), K=256.
// Block M=64 x N=128, 4 waves 2x2, two 128-wide K chunks through LDS.
// ---------------------------------------------------------------------------
__global__ __launch_bounds__(256) void k_gemm(
        const u16* __restrict__ Ah, const u16* __restrict__ Am,
        const u16* __restrict__ Wt, const float* __restrict__ bias,
        void* __restrict__ outp, int relu, int f32out) {
    const int row0 = blockIdx.x * 64;

    __shared__ u16 As[64 * LDA];    // 17.0 KB
    __shared__ u16 Ws[128 * LDA];   // 34.8 KB

    const int tid  = (int)threadIdx.x;
    const int lane = tid & 63;
    const int wave = tid >> 6;
    const int wm = wave & 1;    // row band (32 rows)
    const int wn = wave >> 1;   // col half (64 cols)
    const int m  = lane & 31;
    const int kh = lane >> 5;   // k-half within 16-chunk

    f32x16 acc0, acc1;
#pragma unroll
    for (int i = 0; i < 16; ++i) { acc0[i] = 0.0f; acc1[i] = 0.0f; }

    const u16* ap  = &As[(wm * 32 + m) * LDA + kh * 8];
    const u16* bp0 = &Ws[(wn * 64 + m) * LDA + kh * 8];
    const u16* bp1 = bp0 + 32 * LDA;

#pragma unroll
    for (int c = 0; c < 2; ++c) {
        const u16* __restrict__ Asrc = c ? Am : Ah;
        const int koff = c * 128;
        if (c) __syncthreads();      // protect LDS reuse across chunks
        // stage A chunk: 64 rows x 128 bf16 = 1024 x 16B
        for (int t = tid; t < 1024; t += 256) {
            int r = t >> 4, cc = t & 15;
            int row = row0 + r; if (row >= N_NODES) row = N_NODES - 1;
            *(float4*)&As[r * LDA + cc * 8] =
                ((const float4*)&Asrc[(size_t)row * D])[cc];
        }
        // stage W chunk: 128 n-rows x 128 bf16 (cols koff..koff+127)
        for (int t = tid; t < 2048; t += 256) {
            int r = t >> 4, cc = t & 15;
            *(float4*)&Ws[r * LDA + cc * 8] =
                *(const float4*)&Wt[(size_t)r * K2 + koff + cc * 8];
        }
        __syncthreads();
#pragma unroll
        for (int kk = 0; kk < 8; ++kk) {
            bf16x8 a  = *(const bf16x8*)(ap  + kk * 16);
            bf16x8 b0 = *(const bf16x8*)(bp0 + kk * 16);
            bf16x8 b1 = *(const bf16x8*)(bp1 + kk * 16);
            acc0 = __builtin_amdgcn_mfma_f32_32x32x16_bf16(a, b0, acc0, 0, 0, 0);
            acc1 = __builtin_amdgcn_mfma_f32_32x32x16_bf16(a, b1, acc1, 0, 0, 0);
        }
    }

    // epilogue: C/D layout: col = lane&31, row = (r&3) + 8*(r>>2) + 4*(lane>>5)
    const int c0 = wn * 64 + m;
    const int c1 = c0 + 32;
    const float b0v = bias[c0];
    const float b1v = bias[c1];
#pragma unroll
    for (int r = 0; r < 16; ++r) {
        int rowl = (r & 3) + 8 * (r >> 2) + 4 * kh;
        int grow = row0 + wm * 32 + rowl;
        if (grow < N_NODES) {
            float o0 = acc0[r] + b0v;
            float o1 = acc1[r] + b1v;
            if (relu) { o0 = fmaxf(o0, 0.0f); o1 = fmaxf(o1, 0.0f); }
            if (f32out) {
                ((float*)outp)[(size_t)grow * D + c0] = o0;
                ((float*)outp)[(size_t)grow * D + c1] = o1;
            } else {
                ((u16*)outp)[(size_t)grow * D + c0] = f2b(o0);
                ((u16*)outp)[(size_t)grow * D + c1] = f2b(o1);
            }
        }
    }
}

// ---------------------------------------------------------------------------
// K7: input-aggregate: m[v] = bf16( rcp[v] * sum_{u in csr(v)} h[u] ).
// One 16-lane group per node (4 nodes/wave, 16 nodes/block), 8-deep gather
// pipeline per group. Lists are src-sorted (k_build), so the grid sweeps
// the h table in a moving L2-resident window.
// ---------------------------------------------------------------------------
__global__ __launch_bounds__(256) void k_aggm(
        const u16* __restrict__ h, const int* __restrict__ row_off,
        const u16* __restrict__ degv, const u16* __restrict__ csr,
        const float* __restrict__ rcp, u16* __restrict__ mout) {
    const int g  = (int)threadIdx.x >> 4;   // group 0..15 (node within block)
    const int cl = (int)threadIdx.x & 15;   // lane within group (16B chunk)
    const int v  = (int)blockIdx.x * 16 + g;
    const int beg = row_off[v];
    const int end = beg + (int)degv[v];
    const size_t coff = (size_t)cl * 8;

    float ax[8];
#pragma unroll
    for (int i = 0; i < 8; ++i) ax[i] = 0.0f;

    int j = beg;
    for (; j + 8 <= end; j += 8) {          // 8 gathers in flight per group
        int u0 = csr[j + 0], u1 = csr[j + 1], u2 = csr[j + 2], u3 = csr[j + 3];
        int u4 = csr[j + 4], u5 = csr[j + 5], u6 = csr[j + 6], u7 = csr[j + 7];
        bf16x8 x0 = *(const bf16x8*)&h[(size_t)u0 * D + coff];
        bf16x8 x1 = *(const bf16x8*)&h[(size_t)u1 * D + coff];
        bf16x8 x2 = *(const bf16x8*)&h[(size_t)u2 * D + coff];
        bf16x8 x3 = *(const bf16x8*)&h[(size_t)u3 * D + coff];
        bf16x8 x4 = *(const bf16x8*)&h[(size_t)u4 * D + coff];
        bf16x8 x5 = *(const bf16x8*)&h[(size_t)u5 * D + coff];
        bf16x8 x6 = *(const bf16x8*)&h[(size_t)u6 * D + coff];
        bf16x8 x7 = *(const bf16x8*)&h[(size_t)u7 * D + coff];
#pragma unroll
        for (int i = 0; i < 8; ++i)
            ax[i] += ((b2f((u16)x0[i]) + b2f((u16)x1[i])) +
                      (b2f((u16)x2[i]) + b2f((u16)x3[i]))) +
                     ((b2f((u16)x4[i]) + b2f((u16)x5[i])) +
                      (b2f((u16)x6[i]) + b2f((u16)x7[i])));
    }
    for (; j + 2 <= end; j += 2) {
        int u0 = csr[j], u1 = csr[j + 1];
        bf16x8 x0 = *(const bf16x8*)&h[(size_t)u0 * D + coff];
        bf16x8 x1 = *(const bf16x8*)&h[(size_t)u1 * D + coff];
#pragma unroll
        for (int i = 0; i < 8; ++i)
            ax[i] += b2f((u16)x0[i]) + b2f((u16)x1[i]);
    }
    if (j < end) {
        int u0 = csr[j];
        bf16x8 x0 = *(const bf16x8*)&h[(size_t)u0 * D + coff];
#pragma unroll
        for (int i = 0; i < 8; ++i) ax[i] += b2f((u16)x0[i]);
    }

    const float r = rcp[v];
    uint4 p;
    p.x = (u32)f2b(ax[0] * r) | ((u32)f2b(ax[1] * r) << 16);
    p.y = (u32)f2b(ax[2] * r) | ((u32)f2b(ax[3] * r) << 16);
    p.z = (u32)f2b(ax[4] * r) | ((u32)f2b(ax[5] * r) << 16);
    p.w = (u32)f2b(ax[6] * r) | ((u32)f2b(ax[7] * r) << 16);
    *(uint4*)&mout[(size_t)v * D + coff] = p;
}

// ---------------------------------------------------------------------------
extern "C" void kernel_launch(void* const* d_in, const int* in_sizes, int n_in,
                              void* d_out, int out_size, void* d_ws, size_t ws_size,
                              hipStream_t stream) {
    const float* features = (const float*)d_in[0];
    const int*   edge_src = (const int*)d_in[1];
    const int*   edge_dst = (const int*)d_in[2];
    const float* Wself[3] = {(const float*)d_in[3], (const float*)d_in[6], (const float*)d_in[9]};
    const float* Wngh[3]  = {(const float*)d_in[4], (const float*)d_in[7], (const float*)d_in[10]};
    const float* bias[3]  = {(const float*)d_in[5], (const float*)d_in[8], (const float*)d_in[11]};
    float* out = (float*)d_out;

    char* ws = (char*)d_ws;
    size_t off = 0;
    auto alloc = [&](size_t bytes) {
        char* p = ws + off;
        off += (bytes + 255) & ~(size_t)255;
        return p;
    };
    int*   gbfill  = (int*)alloc(256 * sizeof(int));
    int*   row_off = (int*)alloc(N_NODES * sizeof(int));
    u16*   degv    = (u16*)alloc(N_NODES * sizeof(u16));
    float* rcp     = (float*)alloc(N_NODES * sizeof(float));
    u32*   ebuf    = (u32*)alloc((size_t)NBKT * BCAP * sizeof(u32));
    u16*   csr     = (u16*)alloc((size_t)NBKT * BCAP * sizeof(u16));
    u16*   xa      = (u16*)alloc((size_t)N_NODES * D * sizeof(u16));
    u16*   xb      = (u16*)alloc((size_t)N_NODES * D * sizeof(u16));
    u16*   mb      = (u16*)alloc((size_t)N_NODES * D * sizeof(u16));
    u16*   wt      = (u16*)alloc((size_t)3 * D * K2 * sizeof(u16));

    hipMemsetAsync(gbfill, 0, 256 * sizeof(int), stream);

    // CSR build (fixed-capacity buckets; src-sorted lists for L2 sweep)
    k_part<<<(N_EDGES + EPB - 1) / EPB, 256, 0, stream>>>(edge_src, edge_dst, gbfill, ebuf);
    k_build<<<NBKT, 256, 0, stream>>>(ebuf, gbfill, row_off, degv, rcp, csr);

    // bf16 prep
    k_cast<<<(N_NODES * (D / 8) + 255) / 256, 256, 0, stream>>>(features, xa);
    k_prepw<<<dim3(8, 3), 256, 0, stream>>>(Wself[0], Wngh[0], Wself[1], Wngh[1],
                                            Wself[2], Wngh[2], wt);

    const int gemm_gx = (N_NODES + 63) / 64;
    const int agg_gx  = (N_NODES + 15) / 16;   // 16 nodes per block
    const size_t WSZ = (size_t)D * K2;

    // layer 0: xa -> xb (relu)
    k_aggm<<<agg_gx, 256, 0, stream>>>(xa, row_off, degv, csr, rcp, mb);
    k_gemm<<<gemm_gx, 256, 0, stream>>>(xa, mb, wt + 0 * WSZ, bias[0], xb, 1, 0);
    // layer 1: xb -> xa (relu)
    k_aggm<<<agg_gx, 256, 0, stream>>>(xb, row_off, degv, csr, rcp, mb);
    k_gemm<<<gemm_gx, 256, 0, stream>>>(xb, mb, wt + 1 * WSZ, bias[1], xa, 1, 0);
    // layer 2: xa -> out (f32, no act)
    k_aggm<<<agg_gx, 256, 0, stream>>>(xa, row_off, degv, csr, rcp, mb);
    k_gemm<<<gemm_gx, 256, 0, stream>>>(xa, mb, wt + 2 * WSZ, bias[2], out, 0, 1);
}

// Round 5
// 259.800 us; speedup vs baseline: 1.2596x; 1.0332x over previous
//
#include <hip/hip_runtime.h>

#define N_NODES 50000
#define N_EDGES 800000
#define D 128
#define K2 256                         // fused GEMM K dimension
#define NBKT 196                       // buckets of 256 nodes
#define BCAP 8192                      // fixed slots per bucket
#define EPB 2048                       // edges per k_part block
#define LDA 136                        // LDS row stride in ushorts (128 + 8 pad)
#define ZROW N_NODES                   // zero feature row (padding sentinel)

#define PART_NB ((N_EDGES + EPB - 1) / EPB)       // 391
#define PREPW_NB 24
#define CAST_NB (N_NODES * (D / 8) / 256 + 1)     // 3125 data + 1 zero-row
#define COMBO_NB (PART_NB + PREPW_NB + CAST_NB)

typedef unsigned short u16;
typedef unsigned int   u32;
typedef short bf16x8 __attribute__((ext_vector_type(8)));
typedef float f32x16 __attribute__((ext_vector_type(16)));

// f32 -> bf16 (round-to-nearest-even)
__device__ __forceinline__ u16 f2b(float x) {
    union { float f; u32 u; } c; c.f = x;
    u32 r = c.u + 0x7FFFu + ((c.u >> 16) & 1u);
    return (u16)(r >> 16);
}
__device__ __forceinline__ float b2f(u16 u) {
    union { u32 u; float f; } c; c.u = ((u32)u) << 16;
    return c.f;
}

// ---------------------------------------------------------------------------
// combo sub-kernel 1: partition edges into fixed-capacity bucket chunks.
// Record: u32 = src (16b) | local_node (8b) << 16.
// ---------------------------------------------------------------------------
__device__ void dev_part(int bid, unsigned long long* arena,
                         const int* __restrict__ src,
                         const int* __restrict__ dst,
                         int* __restrict__ gbfill,
                         u32* __restrict__ ebuf) {
    u16* ls  = (u16*)arena;
    u16* ld_ = ls + EPB;
    int* hist  = (int*)(ld_ + EPB);
    int* lcnt  = hist + NBKT;
    int* basev = lcnt + NBKT;
    const int e0 = bid * EPB;
    for (int t = threadIdx.x; t < NBKT; t += 256) { hist[t] = 0; lcnt[t] = 0; }
    __syncthreads();
#pragma unroll
    for (int j = 0; j < EPB / 256; ++j) {
        int t = j * 256 + (int)threadIdx.x;
        int e = e0 + t;
        if (e < N_EDGES) {
            int d = dst[e];
            ls[t] = (u16)src[e];
            ld_[t] = (u16)d;
            atomicAdd(&hist[d >> 8], 1);
        }
    }
    __syncthreads();
    for (int t = threadIdx.x; t < NBKT; t += 256)
        basev[t] = t * BCAP + (hist[t] ? atomicAdd(&gbfill[t], hist[t]) : 0);
    __syncthreads();
#pragma unroll
    for (int j = 0; j < EPB / 256; ++j) {
        int t = j * 256 + (int)threadIdx.x;
        int e = e0 + t;
        if (e < N_EDGES) {
            int d = (int)ld_[t];
            int b = d >> 8;
            int o = atomicAdd(&lcnt[b], 1);
            ebuf[basev[b] + o] = (u32)ls[t] | ((u32)(d & 255) << 16);
        }
    }
}

// ---------------------------------------------------------------------------
// combo sub-kernel 2: build concatenated transposed weights per layer:
// Wcat[l][n][k], k in [0,256): k<128 from W_self[l], k>=128 from W_neigh[l].
// w = flattened (bx, by): bx = w&7 (32-wide k chunk), by = w>>3 (layer).
// ---------------------------------------------------------------------------
__device__ void dev_prepw(int w, unsigned long long* arena,
                          const float* __restrict__ w0, const float* __restrict__ w1,
                          const float* __restrict__ w2, const float* __restrict__ w3,
                          const float* __restrict__ w4, const float* __restrict__ w5,
                          u16* __restrict__ wt) {
    const int bx = w & 7, by = w >> 3;
    const int idx = by * 2 + (bx >= 4 ? 1 : 0);
    const float* W;
    switch (idx) {
        case 0: W = w0; break; case 1: W = w1; break; case 2: W = w2; break;
        case 3: W = w3; break; case 4: W = w4; break; default: W = w5; break;
    }
    u16* out = wt + (size_t)by * D * K2;
    const int k0g = bx * 32;               // global k in [0,256)
    const int k0s = k0g & (D - 1);         // source row in [0,128)
    float (*s)[129] = (float(*)[129])arena;
    for (int t = threadIdx.x; t < 32 * 32; t += 256) {
        int r = t >> 5, c4 = t & 31;
        float4 v = ((const float4*)&W[(size_t)(k0s + r) * D])[c4];
        s[r][c4 * 4 + 0] = v.x; s[r][c4 * 4 + 1] = v.y;
        s[r][c4 * 4 + 2] = v.z; s[r][c4 * 4 + 3] = v.w;
    }
    __syncthreads();
    for (int t = threadIdx.x; t < 512; t += 256) {
        int n = t >> 2, g = t & 3;
        uint4 p;
        p.x = (u32)f2b(s[g * 8 + 0][n]) | ((u32)f2b(s[g * 8 + 1][n]) << 16);
        p.y = (u32)f2b(s[g * 8 + 2][n]) | ((u32)f2b(s[g * 8 + 3][n]) << 16);
        p.z = (u32)f2b(s[g * 8 + 4][n]) | ((u32)f2b(s[g * 8 + 5][n]) << 16);
        p.w = (u32)f2b(s[g * 8 + 6][n]) | ((u32)f2b(s[g * 8 + 7][n]) << 16);
        *(uint4*)&out[(size_t)n * K2 + k0g + g * 8] = p;
    }
}

// ---------------------------------------------------------------------------
// combo sub-kernel 3: cast features f32 -> bf16 (8 elems/thread); last block
// zeroes the sentinel row ZROW in both xa and xb.
// ---------------------------------------------------------------------------
__device__ void dev_cast(int c, const float* __restrict__ f,
                         u16* __restrict__ xa, u16* __restrict__ xb) {
    if (c < CAST_NB - 1) {
        int idx = c * 256 + (int)threadIdx.x;
        const float4* fp = (const float4*)(f + (size_t)idx * 8);
        float4 a = fp[0], b = fp[1];
        uint4 p;
        p.x = (u32)f2b(a.x) | ((u32)f2b(a.y) << 16);
        p.y = (u32)f2b(a.z) | ((u32)f2b(a.w) << 16);
        p.z = (u32)f2b(b.x) | ((u32)f2b(b.y) << 16);
        p.w = (u32)f2b(b.z) | ((u32)f2b(b.w) << 16);
        ((uint4*)xa)[idx] = p;
    } else if (threadIdx.x < 32) {
        u16* dstp = (threadIdx.x < 16) ? xa : xb;
        int t = (int)threadIdx.x & 15;
        uint4 z; z.x = 0; z.y = 0; z.z = 0; z.w = 0;
        *(uint4*)&dstp[(size_t)ZROW * D + t * 8] = z;
    }
}

// ---------------------------------------------------------------------------
// K_COMBO: independent prep kernels in one dispatch (block-range split).
// ---------------------------------------------------------------------------
__global__ __launch_bounds__(256) void k_combo(
        const int* __restrict__ esrc, const int* __restrict__ edst,
        int* __restrict__ gbfill, u32* __restrict__ ebuf,
        const float* __restrict__ feat, u16* __restrict__ xa, u16* __restrict__ xb,
        const float* __restrict__ w0, const float* __restrict__ w1,
        const float* __restrict__ w2, const float* __restrict__ w3,
        const float* __restrict__ w4, const float* __restrict__ w5,
        u16* __restrict__ wt) {
    __shared__ unsigned long long arena[2080];   // 16.6 KB, reused per branch
    const int bid = (int)blockIdx.x;
    if (bid < PART_NB) {
        dev_part(bid, arena, esrc, edst, gbfill, ebuf);
    } else if (bid < PART_NB + PREPW_NB) {
        dev_prepw(bid - PART_NB, arena, w0, w1, w2, w3, w4, w5, wt);
    } else {
        dev_cast(bid - PART_NB - PREPW_NB, feat, xa, xb);
    }
}

// ---------------------------------------------------------------------------
// B2: per-bucket build. Degree hist + scan of PADDED degrees (round up to 8)
// -> 16B-aligned per-node CSR segments; padding slots point at ZROW (zero
// feature row) so k_aggm runs a uniform 8-deep gather pipeline with no
// remainder. row_off = absolute padded base; degv = true degree.
// ---------------------------------------------------------------------------
__global__ __launch_bounds__(256) void k_build(const u32* __restrict__ ebuf,
                                               const int* __restrict__ gbfill,
                                               int* __restrict__ row_off,
                                               u16* __restrict__ degv,
                                               float* __restrict__ rcp,
                                               u16* __restrict__ csr) {
    __shared__ int dcnt[256], fcnt[256], sdata[256];
    const int b = blockIdx.x;
    const int beg = b * BCAP;
    const int end = beg + gbfill[b];
    dcnt[threadIdx.x] = 0;
    fcnt[threadIdx.x] = 0;
    __syncthreads();
    for (int j = beg + (int)threadIdx.x; j < end; j += 256)
        atomicAdd(&dcnt[(ebuf[j] >> 16) & 255], 1);
    __syncthreads();
    const int v  = dcnt[threadIdx.x];
    const int pd = (v + 7) & ~7;            // padded degree
    sdata[threadIdx.x] = pd;
    __syncthreads();
#pragma unroll
    for (int off = 1; off < 256; off <<= 1) {
        int t = (threadIdx.x >= (unsigned)off) ? sdata[threadIdx.x - off] : 0;
        __syncthreads();
        sdata[threadIdx.x] += t;
        __syncthreads();
    }
    const int pbase = beg + sdata[threadIdx.x] - pd;  // absolute padded base
    const int node = (b << 8) + (int)threadIdx.x;
    if (node < N_NODES) {
        row_off[node] = pbase;
        degv[node] = (u16)v;
        rcp[node] = 1.0f / (float)max(v, 1);
    }
    __syncthreads();
    dcnt[threadIdx.x] = pbase;              // publish base for the fill pass
    __syncthreads();
    for (int j = beg + (int)threadIdx.x; j < end; j += 256) {
        u32 u = ebuf[j];
        int ln = (u >> 16) & 255;
        int o = atomicAdd(&fcnt[ln], 1);
        csr[dcnt[ln] + o] = (u16)(u & 0xFFFFu);
    }
    if (node < N_NODES) {
        for (int k = v; k < pd; ++k) csr[pbase + k] = (u16)ZROW;
    }
}

// ---------------------------------------------------------------------------
// K6: fused-layer MFMA GEMM: out = act( [h|m] @ Wcat + b ), K=256.
// Block M=64 x N=128, 4 waves 2x2, two 128-wide K chunks through LDS.
// ---------------------------------------------------------------------------
__global__ __launch_bounds__(256) void k_gemm(
        const u16* __restrict__ Ah, const u16* __restrict__ Am,
        const u16* __restrict__ Wt, const float* __restrict__ bias,
        void* __restrict__ outp, int relu, int f32out) {
    const int row0 = blockIdx.x * 64;

    __shared__ u16 As[64 * LDA];    // 17.0 KB
    __shared__ u16 Ws[128 * LDA];   // 34.8 KB

    const int tid  = (int)threadIdx.x;
    const int lane = tid & 63;
    const int wave = tid >> 6;
    const int wm = wave & 1;    // row band (32 rows)
    const int wn = wave >> 1;   // col half (64 cols)
    const int m  = lane & 31;
    const int kh = lane >> 5;   // k-half within 16-chunk

    f32x16 acc0, acc1;
#pragma unroll
    for (int i = 0; i < 16; ++i) { acc0[i] = 0.0f; acc1[i] = 0.0f; }

    const u16* ap  = &As[(wm * 32 + m) * LDA + kh * 8];
    const u16* bp0 = &Ws[(wn * 64 + m) * LDA + kh * 8];
    const u16* bp1 = bp0 + 32 * LDA;

#pragma unroll
    for (int c = 0; c < 2; ++c) {
        const u16* __restrict__ Asrc = c ? Am : Ah;
        const int koff = c * 128;
        if (c) __syncthreads();      // protect LDS reuse across chunks
        // stage A chunk: 64 rows x 128 bf16 = 1024 x 16B
        for (int t = tid; t < 1024; t += 256) {
            int r = t >> 4, cc = t & 15;
            int row = row0 + r; if (row >= N_NODES) row = N_NODES - 1;
            *(float4*)&As[r * LDA + cc * 8] =
                ((const float4*)&Asrc[(size_t)row * D])[cc];
        }
        // stage W chunk: 128 n-rows x 128 bf16 (cols koff..koff+127)
        for (int t = tid; t < 2048; t += 256) {
            int r = t >> 4, cc = t & 15;
            *(float4*)&Ws[r * LDA + cc * 8] =
                *(const float4*)&Wt[(size_t)r * K2 + koff + cc * 8];
        }
        __syncthreads();
#pragma unroll
        for (int kk = 0; kk < 8; ++kk) {
            bf16x8 a  = *(const bf16x8*)(ap  + kk * 16);
            bf16x8 b0 = *(const bf16x8*)(bp0 + kk * 16);
            bf16x8 b1 = *(const bf16x8*)(bp1 + kk * 16);
            acc0 = __builtin_amdgcn_mfma_f32_32x32x16_bf16(a, b0, acc0, 0, 0, 0);
            acc1 = __builtin_amdgcn_mfma_f32_32x32x16_bf16(a, b1, acc1, 0, 0, 0);
        }
    }

    // epilogue: C/D layout: col = lane&31, row = (r&3) + 8*(r>>2) + 4*(lane>>5)
    const int c0 = wn * 64 + m;
    const int c1 = c0 + 32;
    const float b0v = bias[c0];
    const float b1v = bias[c1];
#pragma unroll
    for (int r = 0; r < 16; ++r) {
        int rowl = (r & 3) + 8 * (r >> 2) + 4 * kh;
        int grow = row0 + wm * 32 + rowl;
        if (grow < N_NODES) {
            float o0 = acc0[r] + b0v;
            float o1 = acc1[r] + b1v;
            if (relu) { o0 = fmaxf(o0, 0.0f); o1 = fmaxf(o1, 0.0f); }
            if (f32out) {
                ((float*)outp)[(size_t)grow * D + c0] = o0;
                ((float*)outp)[(size_t)grow * D + c1] = o1;
            } else {
                ((u16*)outp)[(size_t)grow * D + c0] = f2b(o0);
                ((u16*)outp)[(size_t)grow * D + c1] = f2b(o1);
            }
        }
    }
}

// ---------------------------------------------------------------------------
// K7: input-aggregate: m[v] = bf16( rcp[v] * sum_{u in csr(v)} h[u] ).
// One 16-lane group per node. CSR segments are padded to multiples of 8
// (16B-aligned, padding -> ZROW zeros), so the loop is a single uniform
// 8-deep gather pipeline: one uint4 index load + 8 row-gathers in flight,
// no remainder, no divergence.
// ---------------------------------------------------------------------------
__global__ __launch_bounds__(256) void k_aggm(
        const u16* __restrict__ h, const int* __restrict__ row_off,
        const u16* __restrict__ degv, const u16* __restrict__ csr,
        const float* __restrict__ rcp, u16* __restrict__ mout) {
    const int g  = (int)threadIdx.x >> 4;   // group 0..15 (node within block)
    const int cl = (int)threadIdx.x & 15;   // lane within group (16B chunk)
    const int v  = (int)blockIdx.x * 16 + g;
    const int base = row_off[v];
    const int pend = base + (((int)degv[v] + 7) & ~7);
    const size_t coff = (size_t)cl * 8;

    float ax[8];
#pragma unroll
    for (int i = 0; i < 8; ++i) ax[i] = 0.0f;

    for (int j = base; j < pend; j += 8) {
        uint4 iv = *(const uint4*)&csr[j];      // 8 u16 indices in one load
        int u0 = (int)(iv.x & 0xFFFFu), u1 = (int)(iv.x >> 16);
        int u2 = (int)(iv.y & 0xFFFFu), u3 = (int)(iv.y >> 16);
        int u4 = (int)(iv.z & 0xFFFFu), u5 = (int)(iv.z >> 16);
        int u6 = (int)(iv.w & 0xFFFFu), u7 = (int)(iv.w >> 16);
        bf16x8 x0 = *(const bf16x8*)&h[(size_t)u0 * D + coff];
        bf16x8 x1 = *(const bf16x8*)&h[(size_t)u1 * D + coff];
        bf16x8 x2 = *(const bf16x8*)&h[(size_t)u2 * D + coff];
        bf16x8 x3 = *(const bf16x8*)&h[(size_t)u3 * D + coff];
        bf16x8 x4 = *(const bf16x8*)&h[(size_t)u4 * D + coff];
        bf16x8 x5 = *(const bf16x8*)&h[(size_t)u5 * D + coff];
        bf16x8 x6 = *(const bf16x8*)&h[(size_t)u6 * D + coff];
        bf16x8 x7 = *(const bf16x8*)&h[(size_t)u7 * D + coff];
#pragma unroll
        for (int i = 0; i < 8; ++i)
            ax[i] += ((b2f((u16)x0[i]) + b2f((u16)x1[i])) +
                      (b2f((u16)x2[i]) + b2f((u16)x3[i]))) +
                     ((b2f((u16)x4[i]) + b2f((u16)x5[i])) +
                      (b2f((u16)x6[i]) + b2f((u16)x7[i])));
    }

    const float r = rcp[v];
    uint4 p;
    p.x = (u32)f2b(ax[0] * r) | ((u32)f2b(ax[1] * r) << 16);
    p.y = (u32)f2b(ax[2] * r) | ((u32)f2b(ax[3] * r) << 16);
    p.z = (u32)f2b(ax[4] * r) | ((u32)f2b(ax[5] * r) << 16);
    p.w = (u32)f2b(ax[6] * r) | ((u32)f2b(ax[7] * r) << 16);
    *(uint4*)&mout[(size_t)v * D + coff] = p;
}

// ---------------------------------------------------------------------------
extern "C" void kernel_launch(void* const* d_in, const int* in_sizes, int n_in,
                              void* d_out, int out_size, void* d_ws, size_t ws_size,
                              hipStream_t stream) {
    const float* features = (const float*)d_in[0];
    const int*   edge_src = (const int*)d_in[1];
    const int*   edge_dst = (const int*)d_in[2];
    const float* Wself[3] = {(const float*)d_in[3], (const float*)d_in[6], (const float*)d_in[9]};
    const float* Wngh[3]  = {(const float*)d_in[4], (const float*)d_in[7], (const float*)d_in[10]};
    const float* bias[3]  = {(const float*)d_in[5], (const float*)d_in[8], (const float*)d_in[11]};
    float* out = (float*)d_out;

    char* ws = (char*)d_ws;
    size_t off = 0;
    auto alloc = [&](size_t bytes) {
        char* p = ws + off;
        off += (bytes + 255) & ~(size_t)255;
        return p;
    };
    int*   gbfill  = (int*)alloc(256 * sizeof(int));
    int*   row_off = (int*)alloc(N_NODES * sizeof(int));
    u16*   degv    = (u16*)alloc(N_NODES * sizeof(u16));
    float* rcp     = (float*)alloc(N_NODES * sizeof(float));
    u32*   ebuf    = (u32*)alloc((size_t)NBKT * BCAP * sizeof(u32));
    u16*   csr     = (u16*)alloc((size_t)NBKT * BCAP * sizeof(u16));
    u16*   xa      = (u16*)alloc((size_t)(N_NODES + 8) * D * sizeof(u16));
    u16*   xb      = (u16*)alloc((size_t)(N_NODES + 8) * D * sizeof(u16));
    u16*   mb      = (u16*)alloc((size_t)N_NODES * D * sizeof(u16));
    u16*   wt      = (u16*)alloc((size_t)3 * D * K2 * sizeof(u16));

    hipMemsetAsync(gbfill, 0, 256 * sizeof(int), stream);

    // merged prep: edge partition + weight prep + feature cast (+ zero row)
    k_combo<<<COMBO_NB, 256, 0, stream>>>(edge_src, edge_dst, gbfill, ebuf,
                                          features, xa, xb,
                                          Wself[0], Wngh[0], Wself[1], Wngh[1],
                                          Wself[2], Wngh[2], wt);
    // CSR build with 8-entry padded, 16B-aligned per-node segments
    k_build<<<NBKT, 256, 0, stream>>>(ebuf, gbfill, row_off, degv, rcp, csr);

    const int gemm_gx = (N_NODES + 63) / 64;
    const int agg_gx  = (N_NODES + 15) / 16;   // 16 nodes per block
    const size_t WSZ = (size_t)D * K2;

    // layer 0: xa -> xb (relu)
    k_aggm<<<agg_gx, 256, 0, stream>>>(xa, row_off, degv, csr, rcp, mb);
    k_gemm<<<gemm_gx, 256, 0, stream>>>(xa, mb, wt + 0 * WSZ, bias[0], xb, 1, 0);
    // layer 1: xb -> xa (relu)
    k_aggm<<<agg_gx, 256, 0, stream>>>(xb, row_off, degv, csr, rcp, mb);
    k_gemm<<<gemm_gx, 256, 0, stream>>>(xb, mb, wt + 1 * WSZ, bias[1], xa, 1, 0);
    // layer 2: xa -> out (f32, no act)
    k_aggm<<<agg_gx, 256, 0, stream>>>(xa, row_off, degv, csr, rcp, mb);
    k_gemm<<<gemm_gx, 256, 0, stream>>>(xa, mb, wt + 2 * WSZ, bias[2], out, 0, 1);
}